// Round 16
// baseline (165.978 us; speedup 1.0000x reference)
//
#include <hip/hip_runtime.h>

// GCN 3-layer, R16 = R15 build + windowed fused_l2l3:
//  wave's 8 nodes have contiguous edges [rowptr[n0], rowptr[n0+8]) — process
//  in 64-edge windows: 1 coalesced ew load + 1 per-lane a1 gather + 1
//  ds_write_b128 covers ~4 nodes; consume per node from LDS (uniform
//  ds_read_b128); per-node epilogue (R15 proven) at segment boundaries.
//  Next window prefetched into regs during current consume.

#define BKSH 8                      // 256 nodes per bucket
#define EPB  4096                   // edges per scatter block

__device__ __forceinline__ float rlane(float v, int l) {
    return __int_as_float(__builtin_amdgcn_readlane(__float_as_int(v), l));
}
__device__ __forceinline__ int rlane_i(int v, int l) {
    return __builtin_amdgcn_readlane(v, l);
}

// ---- per-block bucket histogram ----
__global__ void bhist(const int* __restrict__ dst, int* __restrict__ ghist,
                      int E, int NBK, int BLK) {
    __shared__ int h[512];
    int t = threadIdx.x, b = blockIdx.x;
    for (int i = t; i < NBK; i += 256) h[i] = 0;
    __syncthreads();
    int base = b * EPB;
    #pragma unroll
    for (int i = 0; i < 16; ++i) {
        int e = base + i * 256 + t;
        if (e < E) atomicAdd(&h[dst[e] >> BKSH], 1);
    }
    __syncthreads();
    for (int i = t; i < NBK; i += 256) ghist[(size_t)i * BLK + b] = h[i];
}

// ---- exclusive scan phases (block-sum add folded into readers) ----
__global__ void gscan1(const int* __restrict__ in, int* __restrict__ out,
                       int* __restrict__ bsums, int M) {
    __shared__ int tmp[256];
    int i = blockIdx.x * 256 + threadIdx.x;
    int v = (i < M) ? in[i] : 0;
    tmp[threadIdx.x] = v; __syncthreads();
    for (int off = 1; off < 256; off <<= 1) {
        int t = (threadIdx.x >= off) ? tmp[threadIdx.x - off] : 0;
        __syncthreads();
        tmp[threadIdx.x] += t;
        __syncthreads();
    }
    if (i < M) out[i] = tmp[threadIdx.x] - v;
    if (threadIdx.x == 255) bsums[blockIdx.x] = tmp[255];
}

__global__ void gscan2(int* __restrict__ bsums, int nb) {   // 1 block, 1024 thr
    __shared__ int tmp[1024];
    int v = (threadIdx.x < nb) ? bsums[threadIdx.x] : 0;
    tmp[threadIdx.x] = v; __syncthreads();
    for (int off = 1; off < 1024; off <<= 1) {
        int t = (threadIdx.x >= off) ? tmp[threadIdx.x - off] : 0;
        __syncthreads();
        tmp[threadIdx.x] += t;
        __syncthreads();
    }
    if (threadIdx.x < nb) bsums[threadIdx.x] = tmp[threadIdx.x] - v;
}

// ---- scatter edges into bucket-sorted tmp (offsets = goff + gbsums) ----
__global__ void bscatter(const int* __restrict__ src, const int* __restrict__ dst,
                         const int* __restrict__ goff, const int* __restrict__ gbsums,
                         uint2* __restrict__ tmp, int E, int NBK, int BLK) {
    __shared__ int off[512];
    int t = threadIdx.x, b = blockIdx.x;
    for (int i = t; i < NBK; i += 256) {
        size_t m = (size_t)i * BLK + b;
        off[i] = goff[m] + gbsums[m >> 8];
    }
    __syncthreads();
    int base = b * EPB;
    #pragma unroll
    for (int i = 0; i < 16; ++i) {
        int e = base + i * 256 + t;
        if (e < E) {
            int d = dst[e];
            int p = atomicAdd(&off[d >> BKSH], 1);   // LDS-local
            tmp[p] = make_uint2((unsigned)src[e], (unsigned)d);
        }
    }
}

// ---- per-bucket: count + LDS scan -> rowptr + dinv ----
__global__ void bucketA(const uint2* __restrict__ tmp, const int* __restrict__ goff,
                        const int* __restrict__ gbsums, int* __restrict__ rowptr,
                        float* __restrict__ dinv, int N, int NBK, int BLK, int E) {
    __shared__ int lc[256], sc[256];
    int b = blockIdx.x, t = threadIdx.x;
    lc[t] = 0; __syncthreads();
    size_t m0 = (size_t)b * BLK;
    int p0 = goff[m0] + gbsums[m0 >> 8];
    int p1 = E;
    if (b + 1 < NBK) { size_t m1 = (size_t)(b + 1) * BLK; p1 = goff[m1] + gbsums[m1 >> 8]; }
    for (int p = p0 + t; p < p1; p += 256) atomicAdd(&lc[tmp[p].y & 255], 1);
    __syncthreads();
    int v = lc[t];
    sc[t] = v; __syncthreads();
    for (int off = 1; off < 256; off <<= 1) {
        int tv = (t >= off) ? sc[t - off] : 0;
        __syncthreads();
        sc[t] += tv;
        __syncthreads();
    }
    int node = (b << BKSH) + t;
    if (node < N) {
        rowptr[node] = p0 + (sc[t] - v);
        dinv[node]   = rsqrtf((float)(v + 1));
    }
    if (b == 0 && t == 0) rowptr[N] = E;
}

// ---- place edges (dense window) + fused layer-1 aggregation ----
__global__ void fillB(const uint2* __restrict__ tmp, const int* __restrict__ goff,
                      const int* __restrict__ gbsums, const int* __restrict__ rowptr,
                      const float* __restrict__ dinv, const float* __restrict__ x,
                      float2* __restrict__ ew, float4* __restrict__ a1,
                      int N, int NBK, int BLK, int E) {
    __shared__ int   lfill[256];
    __shared__ int   rbase[257];
    __shared__ float ldv[256];
    int b = blockIdx.x, t = threadIdx.x;
    int node0 = b << BKSH;
    lfill[t] = 0;
    int node = node0 + t;
    rbase[t] = rowptr[min(node, N)];
    ldv[t]   = dinv[min(node, N - 1)];
    if (t == 0) rbase[256] = rowptr[min(node0 + 256, N)];
    __syncthreads();
    size_t m0 = (size_t)b * BLK;
    int p0 = goff[m0] + gbsums[m0 >> 8];
    int p1 = E;
    if (b + 1 < NBK) { size_t m1 = (size_t)(b + 1) * BLK; p1 = goff[m1] + gbsums[m1 >> 8]; }
    for (int p = p0 + t; p < p1; p += 256) {
        uint2 e = tmp[p];
        int s = (int)e.x, dl = (int)(e.y & 255);
        float w = dinv[s] * ldv[dl];
        int pos = rbase[dl] + atomicAdd(&lfill[dl], 1);
        ew[pos] = make_float2(__int_as_float(s), w);
    }
    __syncthreads();
    // fused agg3: 16 lane-groups sweep the bucket's 256 nodes (ew L2-hot)
    int grp = t >> 4, sub = t & 15;
    for (int ni = grp; ni < 256; ni += 16) {
        int n = node0 + ni;
        if (n >= N) break;
        int q0 = rbase[ni], q1 = rbase[ni + 1];
        float ax = 0.f, ay = 0.f, az = 0.f;
        for (int p = q0 + sub; p < q1; p += 16) {
            float2 e = ew[p];
            int s = __float_as_int(e.x);
            ax = fmaf(e.y, x[s*3+0], ax);
            ay = fmaf(e.y, x[s*3+1], ay);
            az = fmaf(e.y, x[s*3+2], az);
        }
        #pragma unroll
        for (int off = 8; off; off >>= 1) {
            ax += __shfl_down(ax, off, 16);
            ay += __shfl_down(ay, off, 16);
            az += __shfl_down(az, off, 16);
        }
        if (sub == 0) {
            float dv = ldv[ni], sw = dv * dv;
            a1[n] = make_float4(fmaf(sw, x[n*3+0], ax),
                                fmaf(sw, x[n*3+1], ay),
                                fmaf(sw, x[n*3+2], az), sw);
        }
    }
}

// wc[k] = W3[k][:] @ Wh; wc[64] = b3 @ Wh + bh
__global__ void fold_head(const float* __restrict__ W3, const float* __restrict__ b3,
                          const float* __restrict__ Wh, const float* __restrict__ bh,
                          float* __restrict__ wc) {
    int k = threadIdx.x;              // 64
    float acc = 0.0f;
    for (int f = 0; f < 64; f++) acc += W3[k*64+f] * Wh[f];
    wc[k] = acc;
    if (k == 0) {
        float bb = bh[0];
        for (int f = 0; f < 64; f++) bb += b3[f] * Wh[f];
        wc[64] = bb;
    }
}

// z[n] = relu( (S relu(a1@W1+b1))[n] @ W2 + b2 ) @ wc   (windowed)
__global__ void fused_l2l3(const float2* __restrict__ ew, const int* __restrict__ rowptr,
                           const float4* __restrict__ a1, const float* __restrict__ W1,
                           const float* __restrict__ b1, const float* __restrict__ W2,
                           const float* __restrict__ b2, const float* __restrict__ wc,
                           float* __restrict__ z, int N, int E) {
    __shared__ float  Wl[64*64];
    __shared__ float4 pay[4][64];       // wave-private payload window
    __shared__ float  a2buf[4][64];
    const int tid = threadIdx.x;
    for (int i = tid; i < 4096; i += 256) Wl[i] = W2[i];
    const int lane = tid & 63;
    const int wv   = tid >> 6;
    const float w10 = W1[lane], w11 = W1[64+lane], w12 = W1[128+lane];
    const float b1f = b1[lane], b2f = b2[lane], wcf = wc[lane];
    const int NPW = 8;
    const int n0 = (blockIdx.x * 4 + wv) * NPW;
    int   rpl = rowptr[min(n0 + lane, N)];         // lanes 0..8 used
    float4 sg = a1[min(n0 + lane, N - 1)];         // lanes 0..7 used (self terms)
    __syncthreads();
    if (n0 >= N) return;                           // after barrier: safe
    int NPWv = N - n0; if (NPWv > NPW) NPWv = NPW; // valid nodes (SGPR)
    const int P0 = rlane_i(rpl, 0);
    const int P8 = rlane_i(rpl, NPW);              // = rowptr[min(n0+8,N)]
    int cur = 0;
    // self term of node cur
    float sx = rlane(sg.x, 0), sy = rlane(sg.y, 0);
    float sz2 = rlane(sg.z, 0), sw = rlane(sg.w, 0);
    float ts = fmaf(sz2, w12, fmaf(sy, w11, fmaf(sx, w10, b1f)));
    float acc = sw * fmaxf(ts, 0.f);
    int pos = P0;
    // prologue: load window0 into regs
    float2 e_c = make_float2(0.f, 0.f); float4 g_c = make_float4(0.f,0.f,0.f,0.f);
    if (P0 < P8) {
        int pidx = P0 + lane; if (pidx >= P8) pidx = P8 - 1;
        e_c = ew[pidx];
        g_c = a1[__float_as_int(e_c.x)];
    }
    for (int wbase = P0; wbase < P8; wbase += 64) {
        pay[wv][lane] = make_float4(g_c.x, g_c.y, g_c.z, e_c.y);   // ds_write_b128
        int wend = wbase + 64; if (wend > P8) wend = P8;
        // prefetch next window during consume (VMEM overlaps LDS+VALU)
        int nb = wbase + 64;
        if (nb < P8) {
            int pidx = nb + lane; if (pidx >= P8) pidx = P8 - 1;
            e_c = ew[pidx];
            g_c = a1[__float_as_int(e_c.x)];
        }
        const float4* pp = (const float4*)&pay[wv][0];
        // consume nodes whose segments fall in this window
        bool more = true;
        while (more && cur < NPWv) {
            int p1 = rlane_i(rpl, cur + 1);        // SGPR (uniform)
            int segend = p1 < wend ? p1 : wend;
            int j = pos - wbase, jend = segend - wbase;
            for (; j + 3 < jend; j += 4) {         // uniform ds_read_b128 bcast
                float4 Q0 = pp[j], Q1 = pp[j+1], Q2 = pp[j+2], Q3 = pp[j+3];
                float t0 = fmaf(Q0.z, w12, fmaf(Q0.y, w11, fmaf(Q0.x, w10, b1f)));
                float t1 = fmaf(Q1.z, w12, fmaf(Q1.y, w11, fmaf(Q1.x, w10, b1f)));
                float t2 = fmaf(Q2.z, w12, fmaf(Q2.y, w11, fmaf(Q2.x, w10, b1f)));
                float t3 = fmaf(Q3.z, w12, fmaf(Q3.y, w11, fmaf(Q3.x, w10, b1f)));
                acc = fmaf(Q0.w, fmaxf(t0, 0.f), acc);
                acc = fmaf(Q1.w, fmaxf(t1, 0.f), acc);
                acc = fmaf(Q2.w, fmaxf(t2, 0.f), acc);
                acc = fmaf(Q3.w, fmaxf(t3, 0.f), acc);
            }
            for (; j < jend; ++j) {
                float4 Q = pp[j];
                float tt = fmaf(Q.z, w12, fmaf(Q.y, w11, fmaf(Q.x, w10, b1f)));
                acc = fmaf(Q.w, fmaxf(tt, 0.f), acc);
            }
            pos = segend;
            if (p1 <= wend) {
                // node complete -> epilogue (R15 proven)
                a2buf[wv][lane] = acc;
                float h = b2f;
                const float4* a4 = (const float4*)&a2buf[wv][0];
                #pragma unroll
                for (int k4 = 0; k4 < 16; ++k4) {
                    float4 a = a4[k4];             // uniform broadcast read
                    h = fmaf(a.x, Wl[(4*k4+0)*64 + lane], h);
                    h = fmaf(a.y, Wl[(4*k4+1)*64 + lane], h);
                    h = fmaf(a.z, Wl[(4*k4+2)*64 + lane], h);
                    h = fmaf(a.w, Wl[(4*k4+3)*64 + lane], h);
                }
                float v = fmaxf(h, 0.f) * wcf;
                #pragma unroll
                for (int off = 32; off; off >>= 1) v += __shfl_down(v, off);
                if (lane == 0) z[n0 + cur] = v;
                cur++;
                if (cur < NPWv) {
                    sx = rlane(sg.x, cur); sy = rlane(sg.y, cur);
                    sz2 = rlane(sg.z, cur); sw = rlane(sg.w, cur);
                    ts = fmaf(sz2, w12, fmaf(sy, w11, fmaf(sx, w10, b1f)));
                    acc = sw * fmaxf(ts, 0.f);
                } else more = false;
            } else more = false;
        }
    }
    // drain: nodes with no (remaining) edges — only hit when P0==P8 span empty
    while (cur < NPWv) {
        a2buf[wv][lane] = acc;
        float h = b2f;
        const float4* a4 = (const float4*)&a2buf[wv][0];
        #pragma unroll
        for (int k4 = 0; k4 < 16; ++k4) {
            float4 a = a4[k4];
            h = fmaf(a.x, Wl[(4*k4+0)*64 + lane], h);
            h = fmaf(a.y, Wl[(4*k4+1)*64 + lane], h);
            h = fmaf(a.z, Wl[(4*k4+2)*64 + lane], h);
            h = fmaf(a.w, Wl[(4*k4+3)*64 + lane], h);
        }
        float v = fmaxf(h, 0.f) * wcf;
        #pragma unroll
        for (int off = 32; off; off >>= 1) v += __shfl_down(v, off);
        if (lane == 0) z[n0 + cur] = v;
        cur++;
        if (cur < NPWv) {
            sx = rlane(sg.x, cur); sy = rlane(sg.y, cur);
            sz2 = rlane(sg.z, cur); sw = rlane(sg.w, cur);
            ts = fmaf(sz2, w12, fmaf(sy, w11, fmaf(sx, w10, b1f)));
            acc = sw * fmaxf(ts, 0.f);
        }
    }
}

// logits[n] = dinv^2 z[n] + sum_e w z[s] + c; 16-lane group per node
__global__ void final_wave(const float* __restrict__ z, const float2* __restrict__ ew,
                           const int* __restrict__ rowptr, const float* __restrict__ dinv,
                           const float* __restrict__ wc, float* __restrict__ out, int N) {
    int g   = (blockIdx.x * blockDim.x + threadIdx.x) >> 4;
    int sub = threadIdx.x & 15;
    if (g >= N) return;
    int p0 = rowptr[g], p1 = rowptr[g+1];
    float acc = 0.f;
    for (int p = p0 + sub; p < p1; p += 16) {
        float2 e = ew[p];
        acc = fmaf(e.y, z[__float_as_int(e.x)], acc);
    }
    #pragma unroll
    for (int off = 8; off; off >>= 1) acc += __shfl_down(acc, off, 16);
    if (sub == 0) {
        float dv = dinv[g];
        out[g] = fmaf(dv * dv, z[g], acc) + wc[64];
    }
}

extern "C" void kernel_launch(void* const* d_in, const int* in_sizes, int n_in,
                              void* d_out, int out_size, void* d_ws, size_t ws_size,
                              hipStream_t stream) {
    const float* x   = (const float*)d_in[0];
    const int*   ei  = (const int*)d_in[1];
    const float* W1  = (const float*)d_in[2];
    const float* b1  = (const float*)d_in[3];
    const float* W2  = (const float*)d_in[4];
    const float* b2  = (const float*)d_in[5];
    const float* W3  = (const float*)d_in[6];
    const float* b3  = (const float*)d_in[7];
    const float* Wh  = (const float*)d_in[8];
    const float* bh  = (const float*)d_in[9];
    float* logits = (float*)d_out;

    const int N = in_sizes[0] / 3;
    const int E = in_sizes[1] / 2;
    const int* src = ei;
    const int* dst = ei + E;

    const int NBK = (N + 255) >> BKSH;            // 391 buckets
    const int BLK = (E + EPB - 1) / EPB;          // 391 scatter blocks
    const int M   = NBK * BLK;

    float* base = (float*)d_ws;
    size_t o = 0;
    float*  dinv   = base + o; o += (size_t)N;
    o = (o + 3) & ~(size_t)3;
    float4* a1     = (float4*)(base + o); o += (size_t)4*N;
    int*    rowptr = (int*)(base + o); o += (size_t)N + 1;
    int*    gbsums = (int*)(base + o); o += 1024;
    o = (o + 1) & ~(size_t)1;
    float2* ew     = (float2*)(base + o); o += (size_t)2*E;
    uint2*  tmpb   = (uint2*)(base + o); o += (size_t)2*E;
    float*  zbuf   = base + o; o += (size_t)N;
    float*  wc     = base + o; o += 65;
    int*    ghist  = (int*)(base + o); o += (size_t)M;
    int*    goff   = (int*)(base + o); o += (size_t)M;

    const int BS = 256;
    int gM   = (M + BS - 1) / BS;
    int g16  = ((size_t)N * 16 + BS - 1) / BS;
    int gFU  = (N + 31) / 32;

    bhist    <<<BLK, BS, 0, stream>>>(dst, ghist, E, NBK, BLK);
    gscan1   <<<gM,  BS, 0, stream>>>(ghist, goff, gbsums, M);
    gscan2   <<<1, 1024, 0, stream>>>(gbsums, gM);
    bscatter <<<BLK, BS, 0, stream>>>(src, dst, goff, gbsums, tmpb, E, NBK, BLK);
    bucketA  <<<NBK, BS, 0, stream>>>(tmpb, goff, gbsums, rowptr, dinv, N, NBK, BLK, E);
    fillB    <<<NBK, BS, 0, stream>>>(tmpb, goff, gbsums, rowptr, dinv, x, ew, a1, N, NBK, BLK, E);

    fold_head  <<<1, 64, 0, stream>>>(W3, b3, Wh, bh, wc);
    fused_l2l3 <<<gFU, BS, 0, stream>>>(ew, rowptr, a1, W1, b1, W2, b2, wc, zbuf, N, E);
    final_wave <<<g16, BS, 0, stream>>>(zbuf, ew, rowptr, dinv, wc, logits, N);
}